// Round 5
// baseline (294.554 us; speedup 1.0000x reference)
//
#include <hip/hip_runtime.h>
#include <stdint.h>

#define Tdim 128
#define Zdim 100
#define Sdim 6
#define Hdim 64
#define ZB   3200           // Z*B
#define F1   512
#define F2   128
#define Mrows (ZB * Tdim)   // 409600

typedef _Float16 f16x8 __attribute__((ext_vector_type(8)));
typedef _Float16 f16x4 __attribute__((ext_vector_type(4)));
typedef float f32x4 __attribute__((ext_vector_type(4)));
typedef uint32_t u32x4 __attribute__((ext_vector_type(4)));

__device__ __forceinline__ float sigmoidf_fast(float x) {
  return 1.f / (1.f + __expf(-x));
}
__device__ __forceinline__ float tanhf_fast(float x) {
  return 1.f - 2.f / (__expf(2.f * x) + 1.f);
}

// ---------------------------------------------------------------- prep
// Wf[192][96] fp16: [W_hh | W_ih | 0] row-major per gate (K=96 fused).
// w1p[16][32][72] fp16: per-kt chunk of w1 rows, h-dim padded 64->72.
// w2p[16][128][40] fp16: per-kt k-chunk of w2 (k-major chunks), padded 32->40.
__global__ __launch_bounds__(256) void prep_kernel(
    const float* __restrict__ W_ih, const float* __restrict__ W_hh,
    const float* __restrict__ w1, const float* __restrict__ w2,
    _Float16* __restrict__ Wf, _Float16* __restrict__ w1p,
    _Float16* __restrict__ w2p) {
  int i = blockIdx.x * 256 + threadIdx.x;     // grid covers 137216 exactly
  if (i < 192 * 96) {
    int g = i / 96, k = i - g * 96;
    float v = (k < 64) ? W_hh[g * 64 + k] : ((k < 70) ? W_ih[g * 6 + (k - 64)] : 0.f);
    Wf[i] = (_Float16)v;
  }
  int j = i - 192 * 96;
  if (j >= 0 && j < 16 * 32 * 72) {
    int kt = j / 2304, r = j - kt * 2304;
    int f1 = r / 72, h = r - f1 * 72;
    w1p[j] = (_Float16)((h < 64) ? w1[(kt * 32 + f1) * 64 + h] : 0.f);
  }
  int l = j - 16 * 32 * 72;
  if (l >= 0 && l < 16 * 128 * 40) {
    int kt = l / 5120, r = l - kt * 5120;
    int f2 = r / 40, k = r - f2 * 40;
    w2p[l] = (_Float16)((k < 32) ? w2[f2 * 512 + kt * 32 + k] : 0.f);
  }
}

// ---------------------------------------------------------------- GRU via MFMA
// Block = 4 waves, 16 rows; wave w owns gate-dims [16w,16w+16) of r,z,n.
// KEY: no global stores inside the barrier loop — h history for 64 steps is
// buffered in LDS (hist also serves as the cross-wave h exchange tile), then
// dumped to sx in one coalesced burst per chunk. Barriers drain lgkm only.
__global__ __launch_bounds__(256, 1) void gru_kernel(
    const float* __restrict__ x, const _Float16* __restrict__ Wf,
    const float* __restrict__ b_ih, const float* __restrict__ b_hh,
    _Float16* __restrict__ sx) {
  __shared__ _Float16 hist[64][16][72];       // 144 KB: 64 t-chunk x 16 rows x 64h(+pad)
  const int tid = threadIdx.x;
  const int lane = tid & 63;
  const int w = tid >> 6;                     // wave id 0..3
  const int c = lane & 15;                    // MFMA col = row index
  const int q = lane >> 4;                    // quad

  const int gr0 = w * 16;                     // r-gate tile base
  const int gz0 = 64 + w * 16;                // z-gate tile base
  const int gn0 = 128 + w * 16;               // n-gate tile base

  // A-frags: A[m=c][k=q*8+j] per 16-gate tile, K=96 fused [h|x|0]
  f16x8 Ar[3], Az[3], Anh[2], Ani;
#pragma unroll
  for (int kf = 0; kf < 3; kf++) {
    Ar[kf] = *(const f16x8*)(Wf + (size_t)(gr0 + c) * 96 + kf * 32 + q * 8);
    Az[kf] = *(const f16x8*)(Wf + (size_t)(gz0 + c) * 96 + kf * 32 + q * 8);
  }
  Anh[0] = *(const f16x8*)(Wf + (size_t)(gn0 + c) * 96 + q * 8);
  Anh[1] = *(const f16x8*)(Wf + (size_t)(gn0 + c) * 96 + 32 + q * 8);
  Ani    = *(const f16x8*)(Wf + (size_t)(gn0 + c) * 96 + 64 + q * 8);

  // biases in D-layout (gate-local m = q*4 + r)
  f32x4 Cr, Cz, Cnh, Cni;
  {
    f32x4 bir = *(const f32x4*)(b_ih + gr0 + q * 4);
    f32x4 bhr = *(const f32x4*)(b_hh + gr0 + q * 4);
    f32x4 biz = *(const f32x4*)(b_ih + gz0 + q * 4);
    f32x4 bhz = *(const f32x4*)(b_hh + gz0 + q * 4);
#pragma unroll
    for (int r = 0; r < 4; r++) { Cr[r] = bir[r] + bhr[r]; Cz[r] = biz[r] + bhz[r]; }
    Cnh = *(const f32x4*)(b_hh + gn0 + q * 4);
    Cni = *(const f32x4*)(b_ih + gn0 + q * 4);
  }

  const int n = blockIdx.x * 16 + c;          // n = z*32 + b
  const int zz = n >> 5, bb = n & 31;
  const float* xp = x + (size_t)bb * (Tdim * Zdim * Sdim) + (size_t)zz * Sdim;

  float xv[Sdim];
  if (q == 0) {
#pragma unroll
    for (int s = 0; s < Sdim; s++) xv[s] = xp[s];
  }

  f16x8 Bh0 = {0, 0, 0, 0, 0, 0, 0, 0};
  f16x8 Bh1 = {0, 0, 0, 0, 0, 0, 0, 0};
  f32x4 hprev = {0.f, 0.f, 0.f, 0.f};

  for (int t = 0; t < Tdim; t++) {
    f16x8 Bx = {0, 0, 0, 0, 0, 0, 0, 0};
    if (q == 0) {
      Bx[0] = (_Float16)xv[0]; Bx[1] = (_Float16)xv[1]; Bx[2] = (_Float16)xv[2];
      Bx[3] = (_Float16)xv[3]; Bx[4] = (_Float16)xv[4]; Bx[5] = (_Float16)xv[5];
    }
    // x-projection MFMAs first (independent of h), then h-MFMAs seeded on them
    f32x4 Dni = __builtin_amdgcn_mfma_f32_16x16x32_f16(Ani, Bx, Cni, 0, 0, 0);
    f32x4 Dr  = __builtin_amdgcn_mfma_f32_16x16x32_f16(Ar[2], Bx, Cr, 0, 0, 0);
    f32x4 Dz  = __builtin_amdgcn_mfma_f32_16x16x32_f16(Az[2], Bx, Cz, 0, 0, 0);
    f32x4 Dnh = __builtin_amdgcn_mfma_f32_16x16x32_f16(Anh[0], Bh0, Cnh, 0, 0, 0);
    Dr  = __builtin_amdgcn_mfma_f32_16x16x32_f16(Ar[0], Bh0, Dr, 0, 0, 0);
    Dz  = __builtin_amdgcn_mfma_f32_16x16x32_f16(Az[0], Bh0, Dz, 0, 0, 0);
    Dnh = __builtin_amdgcn_mfma_f32_16x16x32_f16(Anh[1], Bh1, Dnh, 0, 0, 0);
    Dr  = __builtin_amdgcn_mfma_f32_16x16x32_f16(Ar[1], Bh1, Dr, 0, 0, 0);
    Dz  = __builtin_amdgcn_mfma_f32_16x16x32_f16(Az[1], Bh1, Dz, 0, 0, 0);

    // prefetch next x while MFMA completes (drains cheaply: full step in flight)
    if (q == 0 && t + 1 < Tdim) {
      const float* p = xp + (size_t)(t + 1) * (Zdim * Sdim);
#pragma unroll
      for (int s = 0; s < Sdim; s++) xv[s] = p[s];
    }

    f16x4 pk;
#pragma unroll
    for (int r = 0; r < 4; r++) {
      float rr = sigmoidf_fast(Dr[r]);
      float zg = sigmoidf_fast(Dz[r]);
      float nn = tanhf_fast(Dni[r] + rr * Dnh[r]);
      float hnew = nn + zg * (hprev[r] - nn);
      hprev[r] = hnew;
      pk[r] = (_Float16)hnew;
    }
    *(f16x4*)&hist[t & 63][c][w * 16 + q * 4] = pk;
    __syncthreads();                          // lgkm drain only — no vmem stores
    Bh0 = *(const f16x8*)&hist[t & 63][c][q * 8];
    Bh1 = *(const f16x8*)&hist[t & 63][c][32 + q * 8];

    if ((t & 63) == 63) {
      // coalesced dump of the 64-step chunk; wave w handles rows 4w..4w+3
      const int t0 = t - 63;
#pragma unroll
      for (int rr = 0; rr < 4; rr++) {
        const int row = w * 4 + rr;
        const int nrow = blockIdx.x * 16 + row;
        _Float16* dst = sx + (size_t)nrow * Tdim * Hdim + (size_t)t0 * Hdim;
#pragma unroll
        for (int it = 0; it < 8; it++) {
          int idx = it * 64 + lane;           // 0..511
          int tc = idx >> 3, hd8 = idx & 7;
          f16x8 v = *(const f16x8*)&hist[tc][row][hd8 * 8];
          *(f16x8*)(dst + tc * 64 + hd8 * 8) = v;  // lane-contiguous 1 KB/iter
        }
      }
      __syncthreads();                        // dump reads done before reuse
    }
  }
}

// ---------------------------------------------------------------- fused MLP
// Block = 4 waves / 128 rows; weight chunk (14.8 KB/kt) double-buffered in
// LDS (loads for kt+1 issued before compute(kt), committed after, barrier).
// rep is wave-private and single-buffered (in-order LDS). Biases seeded into
// MFMA C-operands. 39.9 KB LDS -> 4 blocks/CU.
__global__ __launch_bounds__(256, 4) void mlp_kernel(
    const _Float16* __restrict__ sx, const _Float16* __restrict__ w1p,
    const _Float16* __restrict__ w2p, const float* __restrict__ b1,
    const float* __restrict__ b2, const float* __restrict__ w3,
    const float* __restrict__ b3, float* __restrict__ out) {
  __shared__ __align__(16) _Float16 w1s[2][32][72];   // 2 x 4608 B
  __shared__ __align__(16) _Float16 w2s[2][128][40];  // 2 x 10240 B
  __shared__ __align__(16) _Float16 rep[4][2][16][40]; // 10240 B, 16B-aligned rows
  const int tid = threadIdx.x;
  const int lane = tid & 63;
  const int wave = tid >> 6;
  const int c = lane & 15;
  const int q = lane >> 4;
  const size_t m0 = ((size_t)blockIdx.x * 4 + wave) * 32;

  // activations (rows) as B-frags for the whole kernel
  f16x8 Bs[2][2];
#pragma unroll
  for (int g = 0; g < 2; g++)
#pragma unroll
    for (int kk = 0; kk < 2; kk++)
      Bs[g][kk] = *(const f16x8*)(sx + (m0 + g * 16 + c) * Hdim + kk * 32 + q * 8);

  // layer2 accumulators seeded with b2 (D row m = nt*16 + q*4 + r)
  f32x4 acc2[2][8];
#pragma unroll
  for (int nt = 0; nt < 8; nt++) {
    f32x4 bb = *(const f32x4*)(b2 + nt * 16 + q * 4);
    acc2[0][nt] = bb;
    acc2[1][nt] = bb;
  }

  u32x4 r1a, r1b, r2a, r2b, r2c;
  // stage kt=0 and commit before the loop
  {
    const u32x4* g1 = (const u32x4*)(w1p);
    const u32x4* g2 = (const u32x4*)(w2p);
    r1a = g1[tid];
    if (tid < 32) r1b = g1[256 + tid];
    r2a = g2[tid];
    r2b = g2[256 + tid];
    if (tid < 128) r2c = g2[512 + tid];
    u32x4* s1 = (u32x4*)&w1s[0][0][0];
    u32x4* s2 = (u32x4*)&w2s[0][0][0];
    s1[tid] = r1a;
    if (tid < 32) s1[256 + tid] = r1b;
    s2[tid] = r2a;
    s2[256 + tid] = r2b;
    if (tid < 128) s2[512 + tid] = r2c;
  }
  __syncthreads();

#pragma unroll 2
  for (int kt = 0; kt < 16; kt++) {
    const int buf = kt & 1;
    // issue loads for kt+1 (land during compute below)
    if (kt + 1 < 16) {
      const u32x4* g1 = (const u32x4*)(w1p + (size_t)(kt + 1) * 2304);
      const u32x4* g2 = (const u32x4*)(w2p + (size_t)(kt + 1) * 5120);
      r1a = g1[tid];
      if (tid < 32) r1b = g1[256 + tid];
      r2a = g2[tid];
      r2b = g2[256 + tid];
      if (tid < 128) r2c = g2[512 + tid];
    }

    // ---- layer1: two 16-wide f1 tiles from w1s[buf], bias-seeded C
#pragma unroll
    for (int ntl = 0; ntl < 2; ntl++) {
      const int f1b = kt * 32 + ntl * 16;
      f16x8 A0 = *(const f16x8*)&w1s[buf][ntl * 16 + c][q * 8];
      f16x8 A1 = *(const f16x8*)&w1s[buf][ntl * 16 + c][32 + q * 8];
      f32x4 bb = *(const f32x4*)(b1 + f1b + q * 4);
#pragma unroll
      for (int g = 0; g < 2; g++) {
        f32x4 cc = __builtin_amdgcn_mfma_f32_16x16x32_f16(A0, Bs[g][0], bb, 0, 0, 0);
        cc = __builtin_amdgcn_mfma_f32_16x16x32_f16(A1, Bs[g][1], cc, 0, 0, 0);
        f16x4 pk;
#pragma unroll
        for (int r = 0; r < 4; r++)
          pk[r] = (_Float16)(cc[r] > 0.f ? cc[r] : 0.f);
        *(f16x4*)&rep[wave][g][c][ntl * 16 + q * 4] = pk;
      }
    }
    // ---- a1 chunk back as B-frags (wave-private LDS, in-order, no barrier)
    f16x8 Ba[2];
#pragma unroll
    for (int g = 0; g < 2; g++)
      Ba[g] = *(const f16x8*)&rep[wave][g][c][q * 8];
    // ---- layer2 partial from w2s[buf]
#pragma unroll
    for (int nt = 0; nt < 8; nt++) {
      f16x8 A2 = *(const f16x8*)&w2s[buf][nt * 16 + c][q * 8];
#pragma unroll
      for (int g = 0; g < 2; g++)
        acc2[g][nt] = __builtin_amdgcn_mfma_f32_16x16x32_f16(A2, Ba[g], acc2[g][nt], 0, 0, 0);
    }

    // ---- commit kt+1 regs -> other LDS buf, then barrier
    if (kt + 1 < 16) {
      u32x4* s1 = (u32x4*)&w1s[buf ^ 1][0][0];
      u32x4* s2 = (u32x4*)&w2s[buf ^ 1][0][0];
      s1[tid] = r1a;
      if (tid < 32) s1[256 + tid] = r1b;
      s2[tid] = r2a;
      s2[256 + tid] = r2b;
      if (tid < 128) s2[512 + tid] = r2c;
      __syncthreads();
    }
  }

  // ---- layer3: out[row] = sum relu(a2) * w3 + b3  (b2 already seeded)
  float part[2] = {0.f, 0.f};
#pragma unroll
  for (int nt = 0; nt < 8; nt++) {
    f32x4 ww = *(const f32x4*)(w3 + nt * 16 + q * 4);
#pragma unroll
    for (int g = 0; g < 2; g++) {
#pragma unroll
      for (int r = 0; r < 4; r++) {
        float v = acc2[g][nt][r];
        v = v > 0.f ? v : 0.f;
        part[g] = fmaf(v, ww[r], part[g]);
      }
    }
  }
#pragma unroll
  for (int g = 0; g < 2; g++) {
    part[g] += __shfl_xor(part[g], 16, 64);
    part[g] += __shfl_xor(part[g], 32, 64);
  }
  if (q < 2) {
    float pv = (q == 0) ? part[0] : part[1];
    out[m0 + q * 16 + c] = pv + b3[0];
  }
}

// ----------------------------------------------------------------
extern "C" void kernel_launch(void* const* d_in, const int* in_sizes, int n_in,
                              void* d_out, int out_size, void* d_ws, size_t ws_size,
                              hipStream_t stream) {
  const float* x    = (const float*)d_in[0];
  const float* W_ih = (const float*)d_in[1];
  const float* W_hh = (const float*)d_in[2];
  const float* b_ih = (const float*)d_in[3];
  const float* b_hh = (const float*)d_in[4];
  const float* w1   = (const float*)d_in[5];
  const float* b1   = (const float*)d_in[6];
  const float* w2   = (const float*)d_in[7];
  const float* b2   = (const float*)d_in[8];
  const float* w3   = (const float*)d_in[9];
  const float* b3   = (const float*)d_in[10];
  float* out = (float*)d_out;

  char* ws = (char*)d_ws;
  _Float16* sxf = (_Float16*)ws;                          // 52,428,800 B
  _Float16* Wf  = (_Float16*)(ws + 52428800);             // 36,864 B
  _Float16* w1p = (_Float16*)(ws + 52428800 + 36864);     // 73,728 B
  _Float16* w2p = (_Float16*)(ws + 52428800 + 36864 + 73728); // 163,840 B

  hipLaunchKernelGGL(prep_kernel, dim3(536), dim3(256), 0, stream,
                     W_ih, W_hh, w1, w2, Wf, w1p, w2p);
  hipLaunchKernelGGL(gru_kernel, dim3(ZB / 16), dim3(256), 0, stream,
                     x, Wf, b_ih, b_hh, sxf);
  hipLaunchKernelGGL(mlp_kernel, dim3(Mrows / 128), dim3(256), 0, stream,
                     sxf, w1p, w2p, b1, b2, w3, b3, out);
}

// Round 6
// 260.945 us; speedup vs baseline: 1.1288x; 1.1288x over previous
//
#include <hip/hip_runtime.h>
#include <stdint.h>

#define Tdim 128
#define Zdim 100
#define Sdim 6
#define Hdim 64
#define ZB   3200           // Z*B
#define F1   512
#define F2   128
#define Mrows (ZB * Tdim)   // 409600

typedef _Float16 f16x8 __attribute__((ext_vector_type(8)));
typedef _Float16 f16x4 __attribute__((ext_vector_type(4)));
typedef float f32x4 __attribute__((ext_vector_type(4)));
typedef uint32_t u32x4 __attribute__((ext_vector_type(4)));

__device__ __forceinline__ float sigmoidf_fast(float x) {
  return 1.f / (1.f + __expf(-x));
}
__device__ __forceinline__ float tanhf_fast(float x) {
  return 1.f - 2.f / (__expf(2.f * x) + 1.f);
}

// ---------------------------------------------------------------- prep
// Wf[192][96] fp16: [W_hh | W_ih | 0] row-major per gate (K=96 fused).
// w1p[16][32][72] fp16: per-kt chunk of w1 rows, h-dim padded 64->72.
// w2p[16][128][40] fp16: per-kt k-chunk of w2 (k-major chunks), padded 32->40.
__global__ __launch_bounds__(256) void prep_kernel(
    const float* __restrict__ W_ih, const float* __restrict__ W_hh,
    const float* __restrict__ w1, const float* __restrict__ w2,
    _Float16* __restrict__ Wf, _Float16* __restrict__ w1p,
    _Float16* __restrict__ w2p) {
  int i = blockIdx.x * 256 + threadIdx.x;     // grid covers 137216 exactly
  if (i < 192 * 96) {
    int g = i / 96, k = i - g * 96;
    float v = (k < 64) ? W_hh[g * 64 + k] : ((k < 70) ? W_ih[g * 6 + (k - 64)] : 0.f);
    Wf[i] = (_Float16)v;
  }
  int j = i - 192 * 96;
  if (j >= 0 && j < 16 * 32 * 72) {
    int kt = j / 2304, r = j - kt * 2304;
    int f1 = r / 72, h = r - f1 * 72;
    w1p[j] = (_Float16)((h < 64) ? w1[(kt * 32 + f1) * 64 + h] : 0.f);
  }
  int l = j - 16 * 32 * 72;
  if (l >= 0 && l < 16 * 128 * 40) {
    int kt = l / 5120, r = l - kt * 5120;
    int f2 = r / 40, k = r - f2 * 40;
    w2p[l] = (_Float16)((k < 32) ? w2[f2 * 512 + kt * 32 + k] : 0.f);
  }
}

// ---------------------------------------------------------------- GRU via MFMA
// Block = 4 waves, 16 rows; wave w owns gate-dims [16w,16w+16) of r,z,n.
// The 128-step loop is globally SILENT: x is preloaded into LDS (fp16,
// B-frag-ready) once; h history kept in a 32-step LDS chunk (also the
// cross-wave exchange tile) and burst-dumped to sx 4x per kernel. Every
// per-step barrier drains lgkmcnt only — no vmem on the serial path.
__global__ __launch_bounds__(256, 1) void gru_kernel(
    const float* __restrict__ x, const _Float16* __restrict__ Wf,
    const float* __restrict__ b_ih, const float* __restrict__ b_hh,
    _Float16* __restrict__ sx) {
  __shared__ __align__(16) _Float16 hist[32][16][72];  // 72 KB
  __shared__ __align__(16) _Float16 xs[Tdim][16][8];   // 32 KB
  const int tid = threadIdx.x;
  const int lane = tid & 63;
  const int w = tid >> 6;                     // wave id 0..3
  const int c = lane & 15;                    // MFMA col = row index
  const int q = lane >> 4;                    // quad

  // ---- preload x for this block's 16 rows, pre-converted to fp16
  for (int i = 0; i < 8; i++) {
    int idx = i * 256 + tid;                  // 0..2047 = (t, row)
    int t = idx >> 4, row = idx & 15;
    int nr = blockIdx.x * 16 + row;           // n = z*32 + b
    const float* p = x + (size_t)(nr & 31) * (Tdim * Zdim * Sdim)
                       + (size_t)t * (Zdim * Sdim) + (size_t)(nr >> 5) * Sdim;
    f16x8 v;
    v[0] = (_Float16)p[0]; v[1] = (_Float16)p[1]; v[2] = (_Float16)p[2];
    v[3] = (_Float16)p[3]; v[4] = (_Float16)p[4]; v[5] = (_Float16)p[5];
    v[6] = (_Float16)0.f;  v[7] = (_Float16)0.f;
    *(f16x8*)&xs[t][row][0] = v;
  }

  const int gr0 = w * 16;                     // r-gate tile base
  const int gz0 = 64 + w * 16;                // z-gate tile base
  const int gn0 = 128 + w * 16;               // n-gate tile base

  // A-frags: A[m=c][k=q*8+j] per 16-gate tile, K=96 fused [h|x|0]
  f16x8 Ar[3], Az[3], Anh[2], Ani;
#pragma unroll
  for (int kf = 0; kf < 3; kf++) {
    Ar[kf] = *(const f16x8*)(Wf + (size_t)(gr0 + c) * 96 + kf * 32 + q * 8);
    Az[kf] = *(const f16x8*)(Wf + (size_t)(gz0 + c) * 96 + kf * 32 + q * 8);
  }
  Anh[0] = *(const f16x8*)(Wf + (size_t)(gn0 + c) * 96 + q * 8);
  Anh[1] = *(const f16x8*)(Wf + (size_t)(gn0 + c) * 96 + 32 + q * 8);
  Ani    = *(const f16x8*)(Wf + (size_t)(gn0 + c) * 96 + 64 + q * 8);

  // biases in D-layout (gate-local m = q*4 + r)
  f32x4 Cr, Cz, Cnh, Cni;
  {
    f32x4 bir = *(const f32x4*)(b_ih + gr0 + q * 4);
    f32x4 bhr = *(const f32x4*)(b_hh + gr0 + q * 4);
    f32x4 biz = *(const f32x4*)(b_ih + gz0 + q * 4);
    f32x4 bhz = *(const f32x4*)(b_hh + gz0 + q * 4);
#pragma unroll
    for (int r = 0; r < 4; r++) { Cr[r] = bir[r] + bhr[r]; Cz[r] = biz[r] + bhz[r]; }
    Cnh = *(const f32x4*)(b_hh + gn0 + q * 4);
    Cni = *(const f32x4*)(b_ih + gn0 + q * 4);
  }

  __syncthreads();                            // xs ready

  f16x8 Bh0 = {0, 0, 0, 0, 0, 0, 0, 0};
  f16x8 Bh1 = {0, 0, 0, 0, 0, 0, 0, 0};
  f32x4 hprev = {0.f, 0.f, 0.f, 0.f};

  for (int t = 0; t < Tdim; t++) {
    const int tc = t & 31;
    // x B-frag from LDS (broadcast read; nonzero only on q==0 lanes)
    f16x8 xv8 = *(const f16x8*)&xs[t][c][0];
    f16x8 Bx;
#pragma unroll
    for (int j = 0; j < 8; j++) Bx[j] = (q == 0) ? xv8[j] : (_Float16)0.f;

    // x-projection MFMAs first (independent of h), then h-MFMAs seeded on them
    f32x4 Dni = __builtin_amdgcn_mfma_f32_16x16x32_f16(Ani, Bx, Cni, 0, 0, 0);
    f32x4 Dr  = __builtin_amdgcn_mfma_f32_16x16x32_f16(Ar[2], Bx, Cr, 0, 0, 0);
    f32x4 Dz  = __builtin_amdgcn_mfma_f32_16x16x32_f16(Az[2], Bx, Cz, 0, 0, 0);
    f32x4 Dnh = __builtin_amdgcn_mfma_f32_16x16x32_f16(Anh[0], Bh0, Cnh, 0, 0, 0);
    Dr  = __builtin_amdgcn_mfma_f32_16x16x32_f16(Ar[0], Bh0, Dr, 0, 0, 0);
    Dz  = __builtin_amdgcn_mfma_f32_16x16x32_f16(Az[0], Bh0, Dz, 0, 0, 0);
    Dnh = __builtin_amdgcn_mfma_f32_16x16x32_f16(Anh[1], Bh1, Dnh, 0, 0, 0);
    Dr  = __builtin_amdgcn_mfma_f32_16x16x32_f16(Ar[1], Bh1, Dr, 0, 0, 0);
    Dz  = __builtin_amdgcn_mfma_f32_16x16x32_f16(Az[1], Bh1, Dz, 0, 0, 0);

    f16x4 pk;
#pragma unroll
    for (int r = 0; r < 4; r++) {
      float rr = sigmoidf_fast(Dr[r]);
      float zg = sigmoidf_fast(Dz[r]);
      float nn = tanhf_fast(Dni[r] + rr * Dnh[r]);
      float hnew = nn + zg * (hprev[r] - nn);
      hprev[r] = hnew;
      pk[r] = (_Float16)hnew;
    }
    *(f16x4*)&hist[tc][c][w * 16 + q * 4] = pk;
    __syncthreads();                          // lgkm-only drain
    Bh0 = *(const f16x8*)&hist[tc][c][q * 8];
    Bh1 = *(const f16x8*)&hist[tc][c][32 + q * 8];

    if (tc == 31) {
      // coalesced dump of the 32-step chunk; wave w handles rows 4w..4w+3
      const int t0 = t - 31;
#pragma unroll
      for (int rr2 = 0; rr2 < 4; rr2++) {
        const int row = w * 4 + rr2;
        const int nrow = blockIdx.x * 16 + row;
        _Float16* dst = sx + (size_t)nrow * Tdim * Hdim + (size_t)t0 * Hdim;
#pragma unroll
        for (int it = 0; it < 4; it++) {
          int idx = it * 64 + lane;           // 0..255
          int tcc = idx >> 3, hd8 = idx & 7;
          f16x8 vv = *(const f16x8*)&hist[tcc][row][hd8 * 8];
          *(f16x8*)(dst + tcc * 64 + hd8 * 8) = vv;  // lane-contiguous 1 KB/iter
        }
      }
      __syncthreads();                        // dump reads done before hist reuse
    }
  }
}

// ---------------------------------------------------------------- fused MLP
// Round-4 proven config: 3 blocks/CU, double-buffered weights AND rep,
// loads(kt+1) -> compute(kt) -> commit(kt+1) -> barrier.
__global__ __launch_bounds__(256, 3) void mlp_kernel(
    const _Float16* __restrict__ sx, const _Float16* __restrict__ w1p,
    const _Float16* __restrict__ w2p, const float* __restrict__ b1,
    const float* __restrict__ b2, const float* __restrict__ w3,
    const float* __restrict__ b3, float* __restrict__ out) {
  __shared__ __align__(16) _Float16 w1s[2][32][72];   // 2 x 4608 B
  __shared__ __align__(16) _Float16 w2s[2][128][40];  // 2 x 10240 B
  __shared__ __align__(16) _Float16 rep[4][2][2][16][36];
  const int tid = threadIdx.x;
  const int lane = tid & 63;
  const int wave = tid >> 6;
  const int c = lane & 15;
  const int q = lane >> 4;
  const size_t m0 = ((size_t)blockIdx.x * 4 + wave) * 32;

  // activations (rows) as B-frags for the whole kernel
  f16x8 Bs[2][2];
#pragma unroll
  for (int g = 0; g < 2; g++)
#pragma unroll
    for (int kk = 0; kk < 2; kk++)
      Bs[g][kk] = *(const f16x8*)(sx + (m0 + g * 16 + c) * Hdim + kk * 32 + q * 8);

  f32x4 acc2[2][8];
#pragma unroll
  for (int g = 0; g < 2; g++)
#pragma unroll
    for (int nt = 0; nt < 8; nt++) acc2[g][nt] = (f32x4){0.f, 0.f, 0.f, 0.f};

  u32x4 r1a, r1b, r2a, r2b, r2c;
  // stage kt=0 and commit before the loop
  {
    const u32x4* g1 = (const u32x4*)(w1p);
    const u32x4* g2 = (const u32x4*)(w2p);
    r1a = g1[tid];
    if (tid < 32) r1b = g1[256 + tid];
    r2a = g2[tid];
    r2b = g2[256 + tid];
    if (tid < 128) r2c = g2[512 + tid];
    u32x4* s1 = (u32x4*)&w1s[0][0][0];
    u32x4* s2 = (u32x4*)&w2s[0][0][0];
    s1[tid] = r1a;
    if (tid < 32) s1[256 + tid] = r1b;
    s2[tid] = r2a;
    s2[256 + tid] = r2b;
    if (tid < 128) s2[512 + tid] = r2c;
  }
  __syncthreads();

#pragma unroll 2
  for (int kt = 0; kt < 16; kt++) {
    const int buf = kt & 1;
    // issue loads for kt+1 (land during compute below)
    if (kt + 1 < 16) {
      const u32x4* g1 = (const u32x4*)(w1p + (size_t)(kt + 1) * 2304);
      const u32x4* g2 = (const u32x4*)(w2p + (size_t)(kt + 1) * 5120);
      r1a = g1[tid];
      if (tid < 32) r1b = g1[256 + tid];
      r2a = g2[tid];
      r2b = g2[256 + tid];
      if (tid < 128) r2c = g2[512 + tid];
    }

    // ---- layer1: two 16-wide f1 tiles from w1s[buf]
#pragma unroll
    for (int ntl = 0; ntl < 2; ntl++) {
      const int f1b = kt * 32 + ntl * 16;
      f16x8 A0 = *(const f16x8*)&w1s[buf][ntl * 16 + c][q * 8];
      f16x8 A1 = *(const f16x8*)&w1s[buf][ntl * 16 + c][32 + q * 8];
      f32x4 bb = *(const f32x4*)(b1 + f1b + q * 4);
#pragma unroll
      for (int g = 0; g < 2; g++) {
        f32x4 cc = {0.f, 0.f, 0.f, 0.f};
        cc = __builtin_amdgcn_mfma_f32_16x16x32_f16(A0, Bs[g][0], cc, 0, 0, 0);
        cc = __builtin_amdgcn_mfma_f32_16x16x32_f16(A1, Bs[g][1], cc, 0, 0, 0);
        f16x4 pk;
#pragma unroll
        for (int r = 0; r < 4; r++) {
          float v = cc[r] + bb[r];
          pk[r] = (_Float16)(v > 0.f ? v : 0.f);
        }
        *(f16x4*)&rep[wave][buf][g][c][ntl * 16 + q * 4] = pk;
      }
    }
    // ---- a1 chunk back as B-frags (wave-private LDS, no barrier)
    f16x8 Ba[2];
#pragma unroll
    for (int g = 0; g < 2; g++) {
      f16x4 lo = *(const f16x4*)&rep[wave][buf][g][c][q * 8];
      f16x4 hi = *(const f16x4*)&rep[wave][buf][g][c][q * 8 + 4];
#pragma unroll
      for (int j = 0; j < 4; j++) { Ba[g][j] = lo[j]; Ba[g][4 + j] = hi[j]; }
    }
    // ---- layer2 partial from w2s[buf]
#pragma unroll
    for (int nt = 0; nt < 8; nt++) {
      f16x8 A2 = *(const f16x8*)&w2s[buf][nt * 16 + c][q * 8];
#pragma unroll
      for (int g = 0; g < 2; g++)
        acc2[g][nt] = __builtin_amdgcn_mfma_f32_16x16x32_f16(A2, Ba[g], acc2[g][nt], 0, 0, 0);
    }

    // ---- commit kt+1 regs -> other LDS buf, then barrier
    if (kt + 1 < 16) {
      u32x4* s1 = (u32x4*)&w1s[buf ^ 1][0][0];
      u32x4* s2 = (u32x4*)&w2s[buf ^ 1][0][0];
      s1[tid] = r1a;
      if (tid < 32) s1[256 + tid] = r1b;
      s2[tid] = r2a;
      s2[256 + tid] = r2b;
      if (tid < 128) s2[512 + tid] = r2c;
      __syncthreads();
    }
  }

  // ---- layer3: out[row] = sum relu(a2 + b2) * w3 + b3
  float part[2] = {0.f, 0.f};
#pragma unroll
  for (int nt = 0; nt < 8; nt++) {
    f32x4 bb = *(const f32x4*)(b2 + nt * 16 + q * 4);
    f32x4 ww = *(const f32x4*)(w3 + nt * 16 + q * 4);
#pragma unroll
    for (int g = 0; g < 2; g++) {
#pragma unroll
      for (int r = 0; r < 4; r++) {
        float v = acc2[g][nt][r] + bb[r];
        v = v > 0.f ? v : 0.f;
        part[g] = fmaf(v, ww[r], part[g]);
      }
    }
  }
#pragma unroll
  for (int g = 0; g < 2; g++) {
    part[g] += __shfl_xor(part[g], 16, 64);
    part[g] += __shfl_xor(part[g], 32, 64);
  }
  if (q < 2) {
    float pv = (q == 0) ? part[0] : part[1];
    out[m0 + q * 16 + c] = pv + b3[0];
  }
}

// ----------------------------------------------------------------
extern "C" void kernel_launch(void* const* d_in, const int* in_sizes, int n_in,
                              void* d_out, int out_size, void* d_ws, size_t ws_size,
                              hipStream_t stream) {
  const float* x    = (const float*)d_in[0];
  const float* W_ih = (const float*)d_in[1];
  const float* W_hh = (const float*)d_in[2];
  const float* b_ih = (const float*)d_in[3];
  const float* b_hh = (const float*)d_in[4];
  const float* w1   = (const float*)d_in[5];
  const float* b1   = (const float*)d_in[6];
  const float* w2   = (const float*)d_in[7];
  const float* b2   = (const float*)d_in[8];
  const float* w3   = (const float*)d_in[9];
  const float* b3   = (const float*)d_in[10];
  float* out = (float*)d_out;

  char* ws = (char*)d_ws;
  _Float16* sxf = (_Float16*)ws;                          // 52,428,800 B
  _Float16* Wf  = (_Float16*)(ws + 52428800);             // 36,864 B
  _Float16* w1p = (_Float16*)(ws + 52428800 + 36864);     // 73,728 B
  _Float16* w2p = (_Float16*)(ws + 52428800 + 36864 + 73728); // 163,840 B

  hipLaunchKernelGGL(prep_kernel, dim3(536), dim3(256), 0, stream,
                     W_ih, W_hh, w1, w2, Wf, w1p, w2p);
  hipLaunchKernelGGL(gru_kernel, dim3(ZB / 16), dim3(256), 0, stream,
                     x, Wf, b_ih, b_hh, sxf);
  hipLaunchKernelGGL(mlp_kernel, dim3(Mrows / 128), dim3(256), 0, stream,
                     sxf, w1p, w2p, b1, b2, w3, b3, out);
}

// Round 7
// 257.405 us; speedup vs baseline: 1.1443x; 1.0138x over previous
//
#include <hip/hip_runtime.h>
#include <stdint.h>

#define Tdim 128
#define Zdim 100
#define Sdim 6
#define Hdim 64
#define ZB   3200           // Z*B
#define F1   512
#define F2   128
#define Mrows (ZB * Tdim)   // 409600

typedef _Float16 f16x8 __attribute__((ext_vector_type(8)));
typedef _Float16 f16x4 __attribute__((ext_vector_type(4)));
typedef float f32x4 __attribute__((ext_vector_type(4)));
typedef uint32_t u32x4 __attribute__((ext_vector_type(4)));

__device__ __forceinline__ float sigmoidf_fast(float x) {
  return 1.f / (1.f + __expf(-x));
}
__device__ __forceinline__ float tanhf_fast(float x) {
  return 1.f - 2.f / (__expf(2.f * x) + 1.f);
}

// ---------------------------------------------------------------- prep
// Wf[192][96] fp16: [W_hh | W_ih | 0] per gate (K=96 fused), for the GRU.
// w1p frag-linear: [kt][ntl][kfrag][lane][8] — each lane's f16x8 A-frag at
//   lane*16B (canonical conflict-free ds_read_b128 pattern).   32768 f16.
// w2p frag-linear: [kt][nt][lane][8].                          65536 f16.
__global__ __launch_bounds__(256) void prep_kernel(
    const float* __restrict__ W_ih, const float* __restrict__ W_hh,
    const float* __restrict__ w1, const float* __restrict__ w2,
    _Float16* __restrict__ Wf, _Float16* __restrict__ w1p,
    _Float16* __restrict__ w2p) {
  int i = blockIdx.x * 256 + threadIdx.x;     // grid covers 116736
  if (i < 192 * 96) {
    int g = i / 96, k = i - g * 96;
    float v = (k < 64) ? W_hh[g * 64 + k] : ((k < 70) ? W_ih[g * 6 + (k - 64)] : 0.f);
    Wf[i] = (_Float16)v;
  }
  int j = i - 192 * 96;
  if (j >= 0 && j < 32768) {
    int kt = j >> 11, ntl = (j >> 10) & 1, kf = (j >> 9) & 1;
    int lane = (j >> 3) & 63, e = j & 7;
    int q = lane >> 4, c = lane & 15;
    int row = kt * 32 + ntl * 16 + c;
    int h = kf * 32 + q * 8 + e;
    w1p[j] = (_Float16)w1[row * 64 + h];
  }
  int l = j - 32768;
  if (l >= 0 && l < 65536) {
    int kt = l >> 12, nt = (l >> 9) & 7;
    int lane = (l >> 3) & 63, e = l & 7;
    int q = lane >> 4, c = lane & 15;
    int row = nt * 16 + c;
    int k = kt * 32 + q * 8 + e;
    w2p[l] = (_Float16)w2[row * 512 + k];
  }
}

// ---------------------------------------------------------------- GRU via MFMA
// Block = 4 waves, 16 rows; wave w owns gate-dims [16w,16w+16) of r,z,n.
// Globally silent 128-step loop (x preloaded to LDS); restructured as
// 4 chunks x 32 steps with #pragma unroll 1 (small body, no I-cache blowup),
// burst dump between chunks.
__global__ __launch_bounds__(256, 1) void gru_kernel(
    const float* __restrict__ x, const _Float16* __restrict__ Wf,
    const float* __restrict__ b_ih, const float* __restrict__ b_hh,
    _Float16* __restrict__ sx) {
  __shared__ __align__(16) _Float16 hist[32][16][72];  // 72 KB
  __shared__ __align__(16) _Float16 xs[Tdim][16][8];   // 32 KB
  const int tid = threadIdx.x;
  const int lane = tid & 63;
  const int w = tid >> 6;                     // wave id 0..3
  const int c = lane & 15;                    // MFMA col = row index
  const int q = lane >> 4;                    // quad

  // ---- preload x for this block's 16 rows, pre-converted to fp16
  for (int i = 0; i < 8; i++) {
    int idx = i * 256 + tid;                  // 0..2047 = (t, row)
    int t = idx >> 4, row = idx & 15;
    int nr = blockIdx.x * 16 + row;           // n = z*32 + b
    const float* p = x + (size_t)(nr & 31) * (Tdim * Zdim * Sdim)
                       + (size_t)t * (Zdim * Sdim) + (size_t)(nr >> 5) * Sdim;
    f16x8 v;
    v[0] = (_Float16)p[0]; v[1] = (_Float16)p[1]; v[2] = (_Float16)p[2];
    v[3] = (_Float16)p[3]; v[4] = (_Float16)p[4]; v[5] = (_Float16)p[5];
    v[6] = (_Float16)0.f;  v[7] = (_Float16)0.f;
    *(f16x8*)&xs[t][row][0] = v;
  }

  const int gr0 = w * 16;                     // r-gate tile base
  const int gz0 = 64 + w * 16;                // z-gate tile base
  const int gn0 = 128 + w * 16;               // n-gate tile base

  // A-frags: A[m=c][k=q*8+j] per 16-gate tile, K=96 fused [h|x|0]
  f16x8 Ar[3], Az[3], Anh[2], Ani;
#pragma unroll
  for (int kf = 0; kf < 3; kf++) {
    Ar[kf] = *(const f16x8*)(Wf + (size_t)(gr0 + c) * 96 + kf * 32 + q * 8);
    Az[kf] = *(const f16x8*)(Wf + (size_t)(gz0 + c) * 96 + kf * 32 + q * 8);
  }
  Anh[0] = *(const f16x8*)(Wf + (size_t)(gn0 + c) * 96 + q * 8);
  Anh[1] = *(const f16x8*)(Wf + (size_t)(gn0 + c) * 96 + 32 + q * 8);
  Ani    = *(const f16x8*)(Wf + (size_t)(gn0 + c) * 96 + 64 + q * 8);

  // biases in D-layout (gate-local m = q*4 + r)
  f32x4 Cr, Cz, Cnh, Cni;
  {
    f32x4 bir = *(const f32x4*)(b_ih + gr0 + q * 4);
    f32x4 bhr = *(const f32x4*)(b_hh + gr0 + q * 4);
    f32x4 biz = *(const f32x4*)(b_ih + gz0 + q * 4);
    f32x4 bhz = *(const f32x4*)(b_hh + gz0 + q * 4);
#pragma unroll
    for (int r = 0; r < 4; r++) { Cr[r] = bir[r] + bhr[r]; Cz[r] = biz[r] + bhz[r]; }
    Cnh = *(const f32x4*)(b_hh + gn0 + q * 4);
    Cni = *(const f32x4*)(b_ih + gn0 + q * 4);
  }

  __syncthreads();                            // xs ready

  f16x8 Bh0 = {0, 0, 0, 0, 0, 0, 0, 0};
  f16x8 Bh1 = {0, 0, 0, 0, 0, 0, 0, 0};
  f32x4 hprev = {0.f, 0.f, 0.f, 0.f};

#pragma unroll 1
  for (int tch = 0; tch < 4; tch++) {
#pragma unroll 1
    for (int tc = 0; tc < 32; tc++) {
      const int t = tch * 32 + tc;
      // x B-frag from LDS (broadcast read; nonzero only on q==0 lanes)
      f16x8 xv8 = *(const f16x8*)&xs[t][c][0];
      f16x8 Bx;
#pragma unroll
      for (int j = 0; j < 8; j++) Bx[j] = (q == 0) ? xv8[j] : (_Float16)0.f;

      f32x4 Dni = __builtin_amdgcn_mfma_f32_16x16x32_f16(Ani, Bx, Cni, 0, 0, 0);
      f32x4 Dr  = __builtin_amdgcn_mfma_f32_16x16x32_f16(Ar[2], Bx, Cr, 0, 0, 0);
      f32x4 Dz  = __builtin_amdgcn_mfma_f32_16x16x32_f16(Az[2], Bx, Cz, 0, 0, 0);
      f32x4 Dnh = __builtin_amdgcn_mfma_f32_16x16x32_f16(Anh[0], Bh0, Cnh, 0, 0, 0);
      Dr  = __builtin_amdgcn_mfma_f32_16x16x32_f16(Ar[0], Bh0, Dr, 0, 0, 0);
      Dz  = __builtin_amdgcn_mfma_f32_16x16x32_f16(Az[0], Bh0, Dz, 0, 0, 0);
      Dnh = __builtin_amdgcn_mfma_f32_16x16x32_f16(Anh[1], Bh1, Dnh, 0, 0, 0);
      Dr  = __builtin_amdgcn_mfma_f32_16x16x32_f16(Ar[1], Bh1, Dr, 0, 0, 0);
      Dz  = __builtin_amdgcn_mfma_f32_16x16x32_f16(Az[1], Bh1, Dz, 0, 0, 0);

      f16x4 pk;
#pragma unroll
      for (int r = 0; r < 4; r++) {
        float rr = sigmoidf_fast(Dr[r]);
        float zg = sigmoidf_fast(Dz[r]);
        float nn = tanhf_fast(Dni[r] + rr * Dnh[r]);
        float hnew = nn + zg * (hprev[r] - nn);
        hprev[r] = hnew;
        pk[r] = (_Float16)hnew;
      }
      *(f16x4*)&hist[tc][c][w * 16 + q * 4] = pk;
      __syncthreads();                        // lgkm-only drain
      Bh0 = *(const f16x8*)&hist[tc][c][q * 8];
      Bh1 = *(const f16x8*)&hist[tc][c][32 + q * 8];
    }
    // coalesced dump of the 32-step chunk; wave w handles rows 4w..4w+3
    {
      const int t0 = tch * 32;
#pragma unroll
      for (int rr2 = 0; rr2 < 4; rr2++) {
        const int row = w * 4 + rr2;
        const int nrow = blockIdx.x * 16 + row;
        _Float16* dst = sx + (size_t)nrow * Tdim * Hdim + (size_t)t0 * Hdim;
#pragma unroll
        for (int it = 0; it < 4; it++) {
          int idx = it * 64 + lane;           // 0..255
          int tcc = idx >> 3, hd8 = idx & 7;
          f16x8 vv = *(const f16x8*)&hist[tcc][row][hd8 * 8];
          *(f16x8*)(dst + tcc * 64 + hd8 * 8) = vv;  // lane-contiguous 1 KB/iter
        }
      }
      __syncthreads();                        // dump reads done before hist reuse
    }
  }
}

// ---------------------------------------------------------------- fused MLP
// Round-4 structure (3 blocks/CU, double-buffered weights AND rep,
// loads(kt+1) -> compute(kt) -> commit(kt+1) -> barrier) with frag-linear
// LDS layouts: every hot ds_read_b128 is lane*16B contiguous (conflict-free).
__global__ __launch_bounds__(256, 3) void mlp_kernel(
    const _Float16* __restrict__ sx, const _Float16* __restrict__ w1p,
    const _Float16* __restrict__ w2p, const float* __restrict__ b1,
    const float* __restrict__ b2, const float* __restrict__ w3,
    const float* __restrict__ b3, float* __restrict__ out) {
  __shared__ __align__(16) _Float16 w1s[2][2048];      // 2 x 4 KB  [ntl][kf][lane][8]
  __shared__ __align__(16) _Float16 w2s[2][4096];      // 2 x 8 KB  [nt][lane][8]
  __shared__ __align__(16) _Float16 rep[4][2][2][512]; // 16 KB     [g][lane][8]
  const int tid = threadIdx.x;
  const int lane = tid & 63;
  const int wave = tid >> 6;
  const int c = lane & 15;
  const int q = lane >> 4;
  const size_t m0 = ((size_t)blockIdx.x * 4 + wave) * 32;

  // activations (rows) as B-frags for the whole kernel
  f16x8 Bs[2][2];
#pragma unroll
  for (int g = 0; g < 2; g++)
#pragma unroll
    for (int kk = 0; kk < 2; kk++)
      Bs[g][kk] = *(const f16x8*)(sx + (m0 + g * 16 + c) * Hdim + kk * 32 + q * 8);

  f32x4 acc2[2][8];
#pragma unroll
  for (int g = 0; g < 2; g++)
#pragma unroll
    for (int nt = 0; nt < 8; nt++) acc2[g][nt] = (f32x4){0.f, 0.f, 0.f, 0.f};

  u32x4 r1, r2a, r2b;
  // stage kt=0 and commit before the loop
  {
    const u32x4* g1 = (const u32x4*)(w1p);
    const u32x4* g2 = (const u32x4*)(w2p);
    r1 = g1[tid];
    r2a = g2[tid];
    r2b = g2[256 + tid];
    ((u32x4*)&w1s[0][0])[tid] = r1;
    ((u32x4*)&w2s[0][0])[tid] = r2a;
    ((u32x4*)&w2s[0][0])[256 + tid] = r2b;
  }
  __syncthreads();

#pragma unroll 2
  for (int kt = 0; kt < 16; kt++) {
    const int buf = kt & 1;
    // issue loads for kt+1 (land during compute below)
    if (kt + 1 < 16) {
      const u32x4* g1 = (const u32x4*)(w1p + (size_t)(kt + 1) * 2048);
      const u32x4* g2 = (const u32x4*)(w2p + (size_t)(kt + 1) * 4096);
      r1 = g1[tid];
      r2a = g2[tid];
      r2b = g2[256 + tid];
    }

    // ---- layer1: two 16-wide f1 tiles; A-frags at lane*16B (conflict-free)
#pragma unroll
    for (int ntl = 0; ntl < 2; ntl++) {
      const int f1b = kt * 32 + ntl * 16;
      f16x8 A0 = *(const f16x8*)&w1s[buf][ntl * 1024 + lane * 8];
      f16x8 A1 = *(const f16x8*)&w1s[buf][ntl * 1024 + 512 + lane * 8];
      f32x4 bb = *(const f32x4*)(b1 + f1b + q * 4);
      // write target: B-frag-linear — lane_b = (2*ntl + q/2)*16 + c, half q&1
      const int roff = ((2 * ntl + (q >> 1)) * 16 + c) * 8 + (q & 1) * 4;
#pragma unroll
      for (int g = 0; g < 2; g++) {
        f32x4 cc = {0.f, 0.f, 0.f, 0.f};
        cc = __builtin_amdgcn_mfma_f32_16x16x32_f16(A0, Bs[g][0], cc, 0, 0, 0);
        cc = __builtin_amdgcn_mfma_f32_16x16x32_f16(A1, Bs[g][1], cc, 0, 0, 0);
        f16x4 pk;
#pragma unroll
        for (int r = 0; r < 4; r++) {
          float v = cc[r] + bb[r];
          pk[r] = (_Float16)(v > 0.f ? v : 0.f);
        }
        *(f16x4*)&rep[wave][buf][g][roff] = pk;
      }
    }
    // ---- a1 chunk back as B-frags: direct lane-linear b128 (conflict-free)
    f16x8 Ba[2];
#pragma unroll
    for (int g = 0; g < 2; g++)
      Ba[g] = *(const f16x8*)&rep[wave][buf][g][lane * 8];
    // ---- layer2 partial; A2 frags at lane*16B (conflict-free)
#pragma unroll
    for (int nt = 0; nt < 8; nt++) {
      f16x8 A2 = *(const f16x8*)&w2s[buf][nt * 512 + lane * 8];
#pragma unroll
      for (int g = 0; g < 2; g++)
        acc2[g][nt] = __builtin_amdgcn_mfma_f32_16x16x32_f16(A2, Ba[g], acc2[g][nt], 0, 0, 0);
    }

    // ---- commit kt+1 regs -> other LDS buf, then barrier
    if (kt + 1 < 16) {
      ((u32x4*)&w1s[buf ^ 1][0])[tid] = r1;
      ((u32x4*)&w2s[buf ^ 1][0])[tid] = r2a;
      ((u32x4*)&w2s[buf ^ 1][0])[256 + tid] = r2b;
      __syncthreads();
    }
  }

  // ---- layer3: out[row] = sum relu(a2 + b2) * w3 + b3
  float part[2] = {0.f, 0.f};
#pragma unroll
  for (int nt = 0; nt < 8; nt++) {
    f32x4 bb = *(const f32x4*)(b2 + nt * 16 + q * 4);
    f32x4 ww = *(const f32x4*)(w3 + nt * 16 + q * 4);
#pragma unroll
    for (int g = 0; g < 2; g++) {
#pragma unroll
      for (int r = 0; r < 4; r++) {
        float v = acc2[g][nt][r] + bb[r];
        v = v > 0.f ? v : 0.f;
        part[g] = fmaf(v, ww[r], part[g]);
      }
    }
  }
#pragma unroll
  for (int g = 0; g < 2; g++) {
    part[g] += __shfl_xor(part[g], 16, 64);
    part[g] += __shfl_xor(part[g], 32, 64);
  }
  if (q < 2) {
    float pv = (q == 0) ? part[0] : part[1];
    out[m0 + q * 16 + c] = pv + b3[0];
  }
}

// ----------------------------------------------------------------
extern "C" void kernel_launch(void* const* d_in, const int* in_sizes, int n_in,
                              void* d_out, int out_size, void* d_ws, size_t ws_size,
                              hipStream_t stream) {
  const float* x    = (const float*)d_in[0];
  const float* W_ih = (const float*)d_in[1];
  const float* W_hh = (const float*)d_in[2];
  const float* b_ih = (const float*)d_in[3];
  const float* b_hh = (const float*)d_in[4];
  const float* w1   = (const float*)d_in[5];
  const float* b1   = (const float*)d_in[6];
  const float* w2   = (const float*)d_in[7];
  const float* b2   = (const float*)d_in[8];
  const float* w3   = (const float*)d_in[9];
  const float* b3   = (const float*)d_in[10];
  float* out = (float*)d_out;

  char* ws = (char*)d_ws;
  _Float16* sxf = (_Float16*)ws;                          // 52,428,800 B
  _Float16* Wf  = (_Float16*)(ws + 52428800);             // 36,864 B
  _Float16* w1p = (_Float16*)(ws + 52428800 + 36864);     // 65,536 B
  _Float16* w2p = (_Float16*)(ws + 52428800 + 36864 + 65536); // 131,072 B

  hipLaunchKernelGGL(prep_kernel, dim3(456), dim3(256), 0, stream,
                     W_ih, W_hh, w1, w2, Wf, w1p, w2p);
  hipLaunchKernelGGL(gru_kernel, dim3(ZB / 16), dim3(256), 0, stream,
                     x, Wf, b_ih, b_hh, sxf);
  hipLaunchKernelGGL(mlp_kernel, dim3(Mrows / 128), dim3(256), 0, stream,
                     sxf, w1p, w2p, b1, b2, w3, b3, out);
}

// Round 8
// 254.999 us; speedup vs baseline: 1.1551x; 1.0094x over previous
//
#include <hip/hip_runtime.h>
#include <stdint.h>

#define Tdim 128
#define Zdim 100
#define Sdim 6
#define Hdim 64
#define ZB   3200           // Z*B
#define F1   512
#define F2   128
#define Mrows (ZB * Tdim)   // 409600

typedef _Float16 f16x8 __attribute__((ext_vector_type(8)));
typedef _Float16 f16x4 __attribute__((ext_vector_type(4)));
typedef float f32x4 __attribute__((ext_vector_type(4)));
typedef uint32_t u32x4 __attribute__((ext_vector_type(4)));

__device__ __forceinline__ float sigmoidf_fast(float x) {
  return 1.f / (1.f + __expf(-x));
}
__device__ __forceinline__ float tanhf_fast(float x) {
  return 1.f - 2.f / (__expf(2.f * x) + 1.f);
}

// ---------------------------------------------------------------- prep
// Wf[192][96] fp16: [W_hh | W_ih | 0] per gate (K=96 fused), for the GRU.
// w1p frag-linear: [kt][ntl][kfrag][lane][8].  32768 f16.
// w2p frag-linear: [kt][nt][lane][8].          65536 f16.
__global__ __launch_bounds__(256) void prep_kernel(
    const float* __restrict__ W_ih, const float* __restrict__ W_hh,
    const float* __restrict__ w1, const float* __restrict__ w2,
    _Float16* __restrict__ Wf, _Float16* __restrict__ w1p,
    _Float16* __restrict__ w2p) {
  int i = blockIdx.x * 256 + threadIdx.x;     // grid covers 116736
  if (i < 192 * 96) {
    int g = i / 96, k = i - g * 96;
    float v = (k < 64) ? W_hh[g * 64 + k] : ((k < 70) ? W_ih[g * 6 + (k - 64)] : 0.f);
    Wf[i] = (_Float16)v;
  }
  int j = i - 192 * 96;
  if (j >= 0 && j < 32768) {
    int kt = j >> 11, ntl = (j >> 10) & 1, kf = (j >> 9) & 1;
    int lane = (j >> 3) & 63, e = j & 7;
    int q = lane >> 4, c = lane & 15;
    int row = kt * 32 + ntl * 16 + c;
    int h = kf * 32 + q * 8 + e;
    w1p[j] = (_Float16)w1[row * 64 + h];
  }
  int l = j - 32768;
  if (l >= 0 && l < 65536) {
    int kt = l >> 12, nt = (l >> 9) & 7;
    int lane = (l >> 3) & 63, e = l & 7;
    int q = lane >> 4, c = lane & 15;
    int row = nt * 16 + c;
    int k = kt * 32 + q * 8 + e;
    w2p[l] = (_Float16)w2[row * 512 + k];
  }
}

// ---------------------------------------------------------------- GRU via MFMA
// Block = 4 waves, 16 rows; wave w owns gate-dims [16w,16w+16) of r,z,n.
// Software-pipelined: the h-independent x-projection MFMAs for step t+1 are
// issued AFTER the hist write and BEFORE the barrier (hidden behind barrier
// skew). h-MFMA chain is 2 dep stages. Loop globally silent; burst dumps.
__global__ __launch_bounds__(256, 1) void gru_kernel(
    const float* __restrict__ x, const _Float16* __restrict__ Wf,
    const float* __restrict__ b_ih, const float* __restrict__ b_hh,
    _Float16* __restrict__ sx) {
  __shared__ __align__(16) _Float16 hist[32][16][72];  // 72 KB
  __shared__ __align__(16) _Float16 xs[Tdim][16][8];   // 32 KB
  const int tid = threadIdx.x;
  const int lane = tid & 63;
  const int w = tid >> 6;                     // wave id 0..3
  const int c = lane & 15;                    // MFMA col = row index
  const int q = lane >> 4;                    // quad

  // ---- preload x for this block's 16 rows, pre-converted to fp16
  for (int i = 0; i < 8; i++) {
    int idx = i * 256 + tid;                  // 0..2047 = (t, row)
    int t = idx >> 4, row = idx & 15;
    int nr = blockIdx.x * 16 + row;           // n = z*32 + b
    const float* p = x + (size_t)(nr & 31) * (Tdim * Zdim * Sdim)
                       + (size_t)t * (Zdim * Sdim) + (size_t)(nr >> 5) * Sdim;
    f16x8 v;
    v[0] = (_Float16)p[0]; v[1] = (_Float16)p[1]; v[2] = (_Float16)p[2];
    v[3] = (_Float16)p[3]; v[4] = (_Float16)p[4]; v[5] = (_Float16)p[5];
    v[6] = (_Float16)0.f;  v[7] = (_Float16)0.f;
    *(f16x8*)&xs[t][row][0] = v;
  }

  const int gr0 = w * 16;                     // r-gate tile base
  const int gz0 = 64 + w * 16;                // z-gate tile base
  const int gn0 = 128 + w * 16;               // n-gate tile base

  // A-frags: A[m=c][k=q*8+j] per 16-gate tile, K=96 fused [h|x|0]
  f16x8 Ar[3], Az[3], Anh[2], Ani;
#pragma unroll
  for (int kf = 0; kf < 3; kf++) {
    Ar[kf] = *(const f16x8*)(Wf + (size_t)(gr0 + c) * 96 + kf * 32 + q * 8);
    Az[kf] = *(const f16x8*)(Wf + (size_t)(gz0 + c) * 96 + kf * 32 + q * 8);
  }
  Anh[0] = *(const f16x8*)(Wf + (size_t)(gn0 + c) * 96 + q * 8);
  Anh[1] = *(const f16x8*)(Wf + (size_t)(gn0 + c) * 96 + 32 + q * 8);
  Ani    = *(const f16x8*)(Wf + (size_t)(gn0 + c) * 96 + 64 + q * 8);

  // biases in D-layout (gate-local m = q*4 + r)
  f32x4 Cr, Cz, Cnh, Cni;
  {
    f32x4 bir = *(const f32x4*)(b_ih + gr0 + q * 4);
    f32x4 bhr = *(const f32x4*)(b_hh + gr0 + q * 4);
    f32x4 biz = *(const f32x4*)(b_ih + gz0 + q * 4);
    f32x4 bhz = *(const f32x4*)(b_hh + gz0 + q * 4);
#pragma unroll
    for (int r = 0; r < 4; r++) { Cr[r] = bir[r] + bhr[r]; Cz[r] = biz[r] + bhz[r]; }
    Cnh = *(const f32x4*)(b_hh + gn0 + q * 4);
    Cni = *(const f32x4*)(b_ih + gn0 + q * 4);
  }

  __syncthreads();                            // xs ready

  f16x8 Bh0 = {0, 0, 0, 0, 0, 0, 0, 0};
  f16x8 Bh1 = {0, 0, 0, 0, 0, 0, 0, 0};
  f32x4 hprev = {0.f, 0.f, 0.f, 0.f};

  // ---- pipeline seeds for t=0: x-projection MFMAs
  f32x4 Dr_s, Dz_s, Dni_s;
  {
    f16x8 xv8 = *(const f16x8*)&xs[0][c][0];
    f16x8 Bx;
#pragma unroll
    for (int j = 0; j < 8; j++) Bx[j] = (q == 0) ? xv8[j] : (_Float16)0.f;
    Dni_s = __builtin_amdgcn_mfma_f32_16x16x32_f16(Ani, Bx, Cni, 0, 0, 0);
    Dr_s  = __builtin_amdgcn_mfma_f32_16x16x32_f16(Ar[2], Bx, Cr, 0, 0, 0);
    Dz_s  = __builtin_amdgcn_mfma_f32_16x16x32_f16(Az[2], Bx, Cz, 0, 0, 0);
  }

#pragma unroll 1
  for (int tch = 0; tch < 4; tch++) {
#pragma unroll 1
    for (int tc = 0; tc < 32; tc++) {
      const int t = tch * 32 + tc;
      // ---- h-dependent MFMAs (2 dep stages), seeded with x-projection
      f32x4 Dnh = __builtin_amdgcn_mfma_f32_16x16x32_f16(Anh[0], Bh0, Cnh, 0, 0, 0);
      f32x4 Dr  = __builtin_amdgcn_mfma_f32_16x16x32_f16(Ar[0], Bh0, Dr_s, 0, 0, 0);
      f32x4 Dz  = __builtin_amdgcn_mfma_f32_16x16x32_f16(Az[0], Bh0, Dz_s, 0, 0, 0);
      Dnh = __builtin_amdgcn_mfma_f32_16x16x32_f16(Anh[1], Bh1, Dnh, 0, 0, 0);
      Dr  = __builtin_amdgcn_mfma_f32_16x16x32_f16(Ar[1], Bh1, Dr, 0, 0, 0);
      Dz  = __builtin_amdgcn_mfma_f32_16x16x32_f16(Az[1], Bh1, Dz, 0, 0, 0);

      f16x4 pk;
#pragma unroll
      for (int r = 0; r < 4; r++) {
        float rr = sigmoidf_fast(Dr[r]);
        float zg = sigmoidf_fast(Dz[r]);
        float nn = tanhf_fast(Dni_s[r] + rr * Dnh[r]);
        float hnew = nn + zg * (hprev[r] - nn);
        hprev[r] = hnew;
        pk[r] = (_Float16)hnew;
      }
      *(f16x4*)&hist[tc][c][w * 16 + q * 4] = pk;

      // ---- pre-barrier: x-projection for t+1 (h-independent, hides behind skew)
      if (t + 1 < Tdim) {
        f16x8 xv8 = *(const f16x8*)&xs[t + 1][c][0];
        f16x8 Bx;
#pragma unroll
        for (int j = 0; j < 8; j++) Bx[j] = (q == 0) ? xv8[j] : (_Float16)0.f;
        Dni_s = __builtin_amdgcn_mfma_f32_16x16x32_f16(Ani, Bx, Cni, 0, 0, 0);
        Dr_s  = __builtin_amdgcn_mfma_f32_16x16x32_f16(Ar[2], Bx, Cr, 0, 0, 0);
        Dz_s  = __builtin_amdgcn_mfma_f32_16x16x32_f16(Az[2], Bx, Cz, 0, 0, 0);
      }
      __syncthreads();                        // lgkm-only drain
      Bh0 = *(const f16x8*)&hist[tc][c][q * 8];
      Bh1 = *(const f16x8*)&hist[tc][c][32 + q * 8];
    }
    // coalesced dump of the 32-step chunk; wave w handles rows 4w..4w+3
    {
      const int t0 = tch * 32;
#pragma unroll
      for (int rr2 = 0; rr2 < 4; rr2++) {
        const int row = w * 4 + rr2;
        const int nrow = blockIdx.x * 16 + row;
        _Float16* dst = sx + (size_t)nrow * Tdim * Hdim + (size_t)t0 * Hdim;
#pragma unroll
        for (int it = 0; it < 4; it++) {
          int idx = it * 64 + lane;           // 0..255
          int tcc = idx >> 3, hd8 = idx & 7;
          f16x8 vv = *(const f16x8*)&hist[tcc][row][hd8 * 8];
          *(f16x8*)(dst + tcc * 64 + hd8 * 8) = vv;  // lane-contiguous 1 KB/iter
        }
      }
      __syncthreads();                        // dump reads done before hist reuse
    }
  }
}

// ---------------------------------------------------------------- fused MLP
// Block = 4 waves / 256 rows; wave = 64 rows (4 groups of 16) so every
// LDS A-frag read feeds 4 MFMAs. Weights double-buffered (loads(kt+1) ->
// compute(kt) -> commit(kt+1) -> barrier); rep single-buffered (wave-private,
// in-order). b1 seeded into MFMA C. 40 KB LDS, 2 blocks/CU.
__global__ __launch_bounds__(256, 2) void mlp_kernel(
    const _Float16* __restrict__ sx, const _Float16* __restrict__ w1p,
    const _Float16* __restrict__ w2p, const float* __restrict__ b1,
    const float* __restrict__ b2, const float* __restrict__ w3,
    const float* __restrict__ b3, float* __restrict__ out) {
  __shared__ __align__(16) _Float16 w1s[2][2048];      // 8 KB  [ntl][kf][lane][8]
  __shared__ __align__(16) _Float16 w2s[2][4096];      // 16 KB [nt][lane][8]
  __shared__ __align__(16) _Float16 rep[4][4][512];    // 16 KB [wave][g][lane*8]
  const int tid = threadIdx.x;
  const int lane = tid & 63;
  const int wave = tid >> 6;
  const int c = lane & 15;
  const int q = lane >> 4;
  const size_t m0 = ((size_t)blockIdx.x * 4 + wave) * 64;

  // activations (rows) as B-frags for the whole kernel: 4 groups of 16 rows
  f16x8 Bs[4][2];
#pragma unroll
  for (int g = 0; g < 4; g++)
#pragma unroll
    for (int kk = 0; kk < 2; kk++)
      Bs[g][kk] = *(const f16x8*)(sx + (m0 + g * 16 + c) * Hdim + kk * 32 + q * 8);

  f32x4 acc2[4][8];
#pragma unroll
  for (int g = 0; g < 4; g++)
#pragma unroll
    for (int nt = 0; nt < 8; nt++) acc2[g][nt] = (f32x4){0.f, 0.f, 0.f, 0.f};

  u32x4 r1, r2a, r2b;
  // stage kt=0 and commit before the loop
  {
    const u32x4* g1 = (const u32x4*)(w1p);
    const u32x4* g2 = (const u32x4*)(w2p);
    r1 = g1[tid];
    r2a = g2[tid];
    r2b = g2[256 + tid];
    ((u32x4*)&w1s[0][0])[tid] = r1;
    ((u32x4*)&w2s[0][0])[tid] = r2a;
    ((u32x4*)&w2s[0][0])[256 + tid] = r2b;
  }
  __syncthreads();

#pragma unroll 1
  for (int kt = 0; kt < 16; kt++) {
    const int buf = kt & 1;
    // issue loads for kt+1 (land during compute below)
    if (kt + 1 < 16) {
      const u32x4* g1 = (const u32x4*)(w1p + (size_t)(kt + 1) * 2048);
      const u32x4* g2 = (const u32x4*)(w2p + (size_t)(kt + 1) * 4096);
      r1 = g1[tid];
      r2a = g2[tid];
      r2b = g2[256 + tid];
    }

    // ---- layer1: two 16-wide f1 tiles; A-frags at lane*16B (conflict-free)
#pragma unroll
    for (int ntl = 0; ntl < 2; ntl++) {
      const int f1b = kt * 32 + ntl * 16;
      f16x8 A0 = *(const f16x8*)&w1s[buf][ntl * 1024 + lane * 8];
      f16x8 A1 = *(const f16x8*)&w1s[buf][ntl * 1024 + 512 + lane * 8];
      f32x4 bb = *(const f32x4*)(b1 + f1b + q * 4);
      // write target: B-frag-linear — lane_b = (2*ntl + q/2)*16 + c, half q&1
      const int roff = ((2 * ntl + (q >> 1)) * 16 + c) * 8 + (q & 1) * 4;
#pragma unroll
      for (int g = 0; g < 4; g++) {
        f32x4 cc = __builtin_amdgcn_mfma_f32_16x16x32_f16(A0, Bs[g][0], bb, 0, 0, 0);
        cc = __builtin_amdgcn_mfma_f32_16x16x32_f16(A1, Bs[g][1], cc, 0, 0, 0);
        f16x4 pk;
#pragma unroll
        for (int r = 0; r < 4; r++)
          pk[r] = (_Float16)(cc[r] > 0.f ? cc[r] : 0.f);
        *(f16x4*)&rep[wave][g][roff] = pk;
      }
    }
    // ---- a1 chunk back as B-frags: direct lane-linear b128 (conflict-free)
    f16x8 Ba[4];
#pragma unroll
    for (int g = 0; g < 4; g++)
      Ba[g] = *(const f16x8*)&rep[wave][g][lane * 8];
    // ---- layer2 partial; A2 frags at lane*16B, each feeds 4 MFMAs
#pragma unroll
    for (int nt = 0; nt < 8; nt++) {
      f16x8 A2 = *(const f16x8*)&w2s[buf][nt * 512 + lane * 8];
#pragma unroll
      for (int g = 0; g < 4; g++)
        acc2[g][nt] = __builtin_amdgcn_mfma_f32_16x16x32_f16(A2, Ba[g], acc2[g][nt], 0, 0, 0);
    }

    // ---- commit kt+1 regs -> other LDS buf, then barrier
    if (kt + 1 < 16) {
      ((u32x4*)&w1s[buf ^ 1][0])[tid] = r1;
      ((u32x4*)&w2s[buf ^ 1][0])[tid] = r2a;
      ((u32x4*)&w2s[buf ^ 1][0])[256 + tid] = r2b;
      __syncthreads();
    }
  }

  // ---- layer3: out[row] = sum relu(a2 + b2) * w3 + b3
  float part[4] = {0.f, 0.f, 0.f, 0.f};
#pragma unroll
  for (int nt = 0; nt < 8; nt++) {
    f32x4 bb = *(const f32x4*)(b2 + nt * 16 + q * 4);
    f32x4 ww = *(const f32x4*)(w3 + nt * 16 + q * 4);
#pragma unroll
    for (int g = 0; g < 4; g++) {
#pragma unroll
      for (int r = 0; r < 4; r++) {
        float v = acc2[g][nt][r] + bb[r];
        v = v > 0.f ? v : 0.f;
        part[g] = fmaf(v, ww[r], part[g]);
      }
    }
  }
#pragma unroll
  for (int g = 0; g < 4; g++) {
    part[g] += __shfl_xor(part[g], 16, 64);
    part[g] += __shfl_xor(part[g], 32, 64);
  }
  // lane (c,q) writes row q*16+c of this wave's 64 rows
  float pv = (q == 0) ? part[0] : (q == 1) ? part[1] : (q == 2) ? part[2] : part[3];
  out[m0 + q * 16 + c] = pv + b3[0];
}

// ----------------------------------------------------------------
extern "C" void kernel_launch(void* const* d_in, const int* in_sizes, int n_in,
                              void* d_out, int out_size, void* d_ws, size_t ws_size,
                              hipStream_t stream) {
  const float* x    = (const float*)d_in[0];
  const float* W_ih = (const float*)d_in[1];
  const float* W_hh = (const float*)d_in[2];
  const float* b_ih = (const float*)d_in[3];
  const float* b_hh = (const float*)d_in[4];
  const float* w1   = (const float*)d_in[5];
  const float* b1   = (const float*)d_in[6];
  const float* w2   = (const float*)d_in[7];
  const float* b2   = (const float*)d_in[8];
  const float* w3   = (const float*)d_in[9];
  const float* b3   = (const float*)d_in[10];
  float* out = (float*)d_out;

  char* ws = (char*)d_ws;
  _Float16* sxf = (_Float16*)ws;                          // 52,428,800 B
  _Float16* Wf  = (_Float16*)(ws + 52428800);             // 36,864 B
  _Float16* w1p = (_Float16*)(ws + 52428800 + 36864);     // 65,536 B
  _Float16* w2p = (_Float16*)(ws + 52428800 + 36864 + 65536); // 131,072 B

  hipLaunchKernelGGL(prep_kernel, dim3(456), dim3(256), 0, stream,
                     W_ih, W_hh, w1, w2, Wf, w1p, w2p);
  hipLaunchKernelGGL(gru_kernel, dim3(ZB / 16), dim3(256), 0, stream,
                     x, Wf, b_ih, b_hh, sxf);
  hipLaunchKernelGGL(mlp_kernel, dim3(Mrows / 256), dim3(256), 0, stream,
                     sxf, w1p, w2p, b1, b2, w3, b3, out);
}